// Round 16
// baseline (85.320 us; speedup 1.0000x reference)
//
#include <hip/hip_runtime.h>
#include <hip/hip_bf16.h>

// ---------------------------------------------------------------------------
// LogicLayer inference (size=1024, prev=1024, batch=16384)
//   out[s,n] = w0[s] + wA[s]*a + wB[s]*b + wAB[s]*a*b,  a = pA@prev, b = pB@prev
// Round 16: m201-faithful 8-barrier phases + A-dbuf/B-TRIPLE-buffer (160KB).
//   Key derivation: every tile's ph1 reads touch ALL four staged units, so
//   units must be confirmed a full tile early; with 2 buffers that forces a
//   stalling vmcnt (r4/r7/r8) or a race (r5/r10). 3rd B-buffer gives B a
//   2-tile stage lead into an idle region: ONE vmcnt(4)/tile confirming
//   loads aged 2-5 phases (>=1200cy; A is L2-hot) -> zero stall, zero WAR.
//   Calendar: ph1 ApA(T+1)->Aalt, ph2 ApB(T+1)->Aalt, ph3 Blo(T+2)->Bidle,
//   ph4 Bhi(T+2)->Bidle + vmcnt(4). Audited incl. prologue + t=14/15 tails.
// ---------------------------------------------------------------------------

typedef __attribute__((ext_vector_type(8))) short bf16x8;
typedef __attribute__((ext_vector_type(4))) float f32x4;

__device__ __forceinline__ void gload_lds16(const void* g, void* l) {
    __builtin_amdgcn_global_load_lds(
        (const __attribute__((address_space(1))) void*)g,
        (__attribute__((address_space(3))) void*)l, 16, 0, 0);
}

// ---------------- kernel 1: fused prep (transpose | softmax | coef) ---------
constexpr int Kp = 1024;     // prev_size
constexpr int Np = 16384;    // batch
constexpr int NTB = (Np / 64) * (Kp / 64);   // 4096 transpose blocks

__global__ __launch_bounds__(256) void prep_fused(
    const float* __restrict__ prev, __hip_bfloat16* __restrict__ prevT,
    const float* __restrict__ WA, const float* __restrict__ WB,
    __hip_bfloat16* __restrict__ PA, __hip_bfloat16* __restrict__ PB,
    const float* __restrict__ TW, float4* __restrict__ coef)
{
    const int bid = blockIdx.x;
    const int t = threadIdx.x;

    if (bid < NTB) {
        __shared__ float ls[64][65];
        const int n0 = (bid & 255) * 64;
        const int k0 = (bid >> 8) * 64;
        {
            const int kr = t >> 4, nc = (t & 15) * 4;
            #pragma unroll
            for (int i = 0; i < 4; ++i) {
                const int k = i * 16 + kr;
                float4 v = *(const float4*)&prev[(size_t)(k0 + k) * Np + n0 + nc];
                ls[k][nc + 0] = v.x; ls[k][nc + 1] = v.y;
                ls[k][nc + 2] = v.z; ls[k][nc + 3] = v.w;
            }
        }
        __syncthreads();
        {
            const int n = t >> 2, kc = (t & 3) * 16;
            __align__(16) __hip_bfloat16 tmp[16];
            #pragma unroll
            for (int j = 0; j < 16; ++j) tmp[j] = __float2bfloat16(ls[kc + j][n]);
            __hip_bfloat16* dst = &prevT[(size_t)(n0 + n) * Kp + k0 + kc];
            *(uint4*)(dst + 0) = *(const uint4*)&tmp[0];
            *(uint4*)(dst + 8) = *(const uint4*)&tmp[8];
        }
        return;
    }

    if (bid < NTB + 2048) {
        const int b = bid - NTB;
        const float* W;
        __hip_bfloat16* P;
        if (b < 1024) { W = WA + (size_t)b * Kp;          P = PA + (size_t)b * Kp; }
        else          { W = WB + (size_t)(b - 1024) * Kp; P = PB + (size_t)(b - 1024) * Kp; }

        const int wave = t >> 6, lane = t & 63;
        float4 v = *(const float4*)&W[t * 4];
        float mx = fmaxf(fmaxf(v.x, v.y), fmaxf(v.z, v.w));
        #pragma unroll
        for (int off = 32; off; off >>= 1) mx = fmaxf(mx, __shfl_xor(mx, off));

        __shared__ float redmax[4];
        __shared__ float redsum[4];
        if (lane == 0) redmax[wave] = mx;
        __syncthreads();
        mx = fmaxf(fmaxf(redmax[0], redmax[1]), fmaxf(redmax[2], redmax[3]));

        float e0 = __expf(v.x - mx), e1 = __expf(v.y - mx);
        float e2 = __expf(v.z - mx), e3 = __expf(v.w - mx);
        float s = e0 + e1 + e2 + e3;
        #pragma unroll
        for (int off = 32; off; off >>= 1) s += __shfl_xor(s, off);
        if (lane == 0) redsum[wave] = s;
        __syncthreads();
        s = redsum[0] + redsum[1] + redsum[2] + redsum[3];

        const float inv = 1.0f / s;
        __align__(8) __hip_bfloat16 o[4];
        o[0] = __float2bfloat16(e0 * inv);
        o[1] = __float2bfloat16(e1 * inv);
        o[2] = __float2bfloat16(e2 * inv);
        o[3] = __float2bfloat16(e3 * inv);
        *(uint2*)&P[t * 4] = *(const uint2*)o;
        return;
    }

    const int s = (bid - NTB - 2048) * 256 + t;
    if (s < 1024) {
        float p[16];
        float mx = -1e30f;
        #pragma unroll
        for (int g = 0; g < 16; ++g) { p[g] = TW[g * 1024 + s]; mx = fmaxf(mx, p[g]); }
        float sum = 0.f;
        #pragma unroll
        for (int g = 0; g < 16; ++g) { p[g] = __expf(p[g] - mx); sum += p[g]; }
        const float inv = 1.0f / sum;
        #pragma unroll
        for (int g = 0; g < 16; ++g) p[g] *= inv;
        float w0  = p[8] + p[9] + p[10] + p[11] + p[12] + p[13] + p[14] + p[15];
        float wA  = p[2] + p[3] + p[6] + p[7] - p[8] - p[9] - p[12] - p[13];
        float wB  = p[4] + p[5] + p[6] + p[7] - p[8] - p[9] - p[10] - p[11];
        float wAB = p[1] - p[2] - p[4] - 2.f * p[6] - p[7]
                  + p[8] + 2.f * p[9] + p[11] + p[13] - p[14];
        coef[s] = make_float4(w0, wA, wB, wAB);
    }
}

// ---------------- kernel 2: 8-barrier dual GEMM, A-dbuf + B-triple ----------
// Block: 256 stacked A-rows (128 pA + 128 pB) x 256 cols, BK=64, 16 K-tiles.
// 8 waves 2(panel)x4(N), per-wave 128x64 out = acc[8][4].
// LDS 160KB: Abuf[2] 32KB @ {0,32768} (ApA +0, ApB +16384);
//            Bbuf[3] 32KB @ {65536,98304,131072} (rows0-127 +0, 128-255 +16K).
// Tile T reads Abuf[T&1], Bbuf[T%3]. Row=128B, chunk-XOR swizzle (r4..r15).
constexpr int Kd = 1024;
constexpr int Nd = 16384;
constexpr int A0_ = 0,     A1_ = 32768;
constexpr int Q0_ = 65536, Q1_ = 98304, Q2_ = 131072;

__global__ __launch_bounds__(512, 2) void dual_gemm8(
    const __hip_bfloat16* __restrict__ pA,
    const __hip_bfloat16* __restrict__ pB,
    const __hip_bfloat16* __restrict__ prevT,
    const float4* __restrict__ coef,
    float* __restrict__ out)
{
    __shared__ __align__(16) char smem[163840];

    const int t_ = threadIdx.x;
    const int wave = t_ >> 6, lane = t_ & 63;
    const int wr = wave >> 2, wc = wave & 3;      // wr: 0=pA panel, 1=pB panel
    const int m0 = blockIdx.y * 128;
    const int n0 = blockIdx.x * 256;

    // fragment-read addressing (relative to the tile's A/B buffer base)
    const int fr  = lane & 15;
    const int kg  = lane >> 4;
    const int fsw = fr & 7;
    const int c0 = (kg ^ fsw) * 16;               // kstep 0 chunk byte
    const int c1 = ((4 + kg) ^ fsw) * 16;         // kstep 1 chunk byte
    const int aoffs = (wr * 128 + fr) * 128;      // + i*2048 (+8192 for i4-7)
    const int boffs = (wc * 64 + fr) * 128;       // + j*2048

    // staging addressing (pre-swizzled global source)
    const int sr  = lane >> 3;
    const int swz = ((lane & 7) ^ sr) * 8;
    const int r0  = wave * 16 + sr;
    const __hip_bfloat16* gA0 = pA    + (size_t)(m0 + r0) * Kd + swz;
    const __hip_bfloat16* gA1 = pB    + (size_t)(m0 + r0) * Kd + swz;
    const __hip_bfloat16* gB0 = prevT + (size_t)(n0 + r0) * Kd + swz;
    const __hip_bfloat16* gB1 = prevT + (size_t)(n0 + 128 + r0) * Kd + swz;

    f32x4 acc[8][4] = {};
    bf16x8 aL[8], aH[8], bL[4], bH[4];

#define STG(GP, BB, HOFF, KT) {                                             \
    char* lb = smem + (BB) + (HOFF) + wave * 2048;                          \
    gload_lds16((GP) + (KT), lb);                                           \
    gload_lds16((GP) + (KT) + 8 * Kd, lb + 1024); }

#define RD_AL(BB) _Pragma("unroll") for (int i = 0; i < 4; ++i) {           \
    aL[i*2]   = *(const bf16x8*)(smem + (BB) + aoffs + i * 2048 + c0);      \
    aL[i*2+1] = *(const bf16x8*)(smem + (BB) + aoffs + i * 2048 + c1); }
#define RD_AH(BB) _Pragma("unroll") for (int i = 0; i < 4; ++i) {           \
    aH[i*2]   = *(const bf16x8*)(smem + (BB) + aoffs + 8192 + i * 2048 + c0); \
    aH[i*2+1] = *(const bf16x8*)(smem + (BB) + aoffs + 8192 + i * 2048 + c1); }
#define RD_BL(BB) _Pragma("unroll") for (int j = 0; j < 2; ++j) {           \
    bL[j*2]   = *(const bf16x8*)(smem + (BB) + boffs + j * 2048 + c0);      \
    bL[j*2+1] = *(const bf16x8*)(smem + (BB) + boffs + j * 2048 + c1); }
#define RD_BH(BB) _Pragma("unroll") for (int j = 0; j < 2; ++j) {           \
    bH[j*2]   = *(const bf16x8*)(smem + (BB) + boffs + 4096 + j * 2048 + c0); \
    bH[j*2+1] = *(const bf16x8*)(smem + (BB) + boffs + 4096 + j * 2048 + c1); }

#define VMW(S)  asm volatile("s_waitcnt " S ::: "memory")
#define LGK(S)  asm volatile("s_waitcnt " S ::: "memory")
#define BAR     __builtin_amdgcn_s_barrier()
#define SBR     __builtin_amdgcn_sched_barrier(0)

#define MMQ(AB, BB, I0, J0)                                                 \
    __builtin_amdgcn_s_setprio(1);                                          \
    _Pragma("unroll") for (int i = 0; i < 4; ++i)                           \
    _Pragma("unroll") for (int j = 0; j < 2; ++j)                           \
    _Pragma("unroll") for (int ks = 0; ks < 2; ++ks)                        \
        acc[(I0)+i][(J0)+j] = __builtin_amdgcn_mfma_f32_16x16x32_bf16(      \
            AB[i*2+ks], BB[(J0 ? 0 : 0)+j*2+ks], acc[(I0)+i][(J0)+j], 0,0,0); \
    __builtin_amdgcn_s_setprio(0);

// One K-tile = 4 template phases (reads+stage pre-barrier; BAR; lgkm0+SBR;
// setprio+16 MFMA; BAR). Stage calendar (audited, zero-stall, zero-WAR):
//   ph1: ApA(T+1)->NA   ph2: ApB(T+1)->NA   ph3: Blo(T+2)->B2  ph4: Bhi->B2
//   ph4 vmcnt(4): confirms {B(T+1) ages 4-5ph, A(T+1) ages 2-3ph (L2-hot)};
//   leaves B(T+2) (4 loads) = entry invariant of T+1.
#define TILE(T, CA, CB, NA, B2, SGA, SGB, DOVM, VMSTR) {                    \
    RD_AL(CA) RD_BL(CB)                                                     \
    if (SGA) STG(gA0, NA, 0, ((T)+1)*64)                                    \
    LGK("lgkmcnt(8)");                                                      \
    BAR; LGK("lgkmcnt(0)"); SBR;                                            \
    MMQ(aL, bL, 0, 0) BAR;                                                  \
    RD_BH(CB)                                                               \
    if (SGA) STG(gA1, NA, 16384, ((T)+1)*64)                                \
    BAR; LGK("lgkmcnt(0)"); SBR;                                            \
    MMQ(aL, bH, 0, 2) BAR;                                                  \
    RD_AH(CA)                                                               \
    if (SGB) STG(gB0, B2, 0, ((T)+2)*64)                                    \
    BAR; LGK("lgkmcnt(0)"); SBR;                                            \
    MMQ(aH, bH, 4, 2) BAR;                                                  \
    if (SGB) STG(gB1, B2, 16384, ((T)+2)*64)                                \
    if (DOVM) VMW(VMSTR);                                                   \
    BAR; SBR;                                                               \
    MMQ(aH, bL, 4, 0) BAR;                                                  \
}

    // prologue: B(0)->Q0, A(0)->A0, B(1)->Q1; vmcnt(4) confirms tile0's 8
    // loads, leaves B(1) (invariant); BAR publishes cross-wave.
    STG(gB0, Q0_, 0,     0)
    STG(gB1, Q0_, 16384, 0)
    STG(gA0, A0_, 0,     0)
    STG(gA1, A0_, 16384, 0)
    STG(gB0, Q1_, 0,     64)
    STG(gB1, Q1_, 16384, 64)
    VMW("vmcnt(4)");
    BAR; SBR;

#define SIX(TB)                                                             \
    TILE((TB)+0, A0_, Q0_, A1_, Q2_, 1, 1, 1, "vmcnt(4)")                   \
    TILE((TB)+1, A1_, Q1_, A0_, Q0_, 1, 1, 1, "vmcnt(4)")                   \
    TILE((TB)+2, A0_, Q2_, A1_, Q1_, 1, 1, 1, "vmcnt(4)")                   \
    TILE((TB)+3, A1_, Q0_, A0_, Q2_, 1, 1, 1, "vmcnt(4)")                   \
    TILE((TB)+4, A0_, Q1_, A1_, Q0_, 1, 1, 1, "vmcnt(4)")                   \
    TILE((TB)+5, A1_, Q2_, A0_, Q1_, 1, 1, 1, "vmcnt(4)")

    SIX(0)
    SIX(6)
    TILE(12, A0_, Q0_, A1_, Q2_, 1, 1, 1, "vmcnt(4)")   // stages A(13), B(14)
    TILE(13, A1_, Q1_, A0_, Q0_, 1, 1, 1, "vmcnt(4)")   // stages A(14), B(15)
    TILE(14, A0_, Q2_, A1_, Q0_, 1, 0, 1, "vmcnt(0)")   // stages A(15); drain
    TILE(15, A1_, Q0_, A0_, Q0_, 0, 0, 0, "vmcnt(0)")   // bare

#undef SIX
#undef TILE
#undef MMQ
#undef STG
#undef RD_AL
#undef RD_AH
#undef RD_BL
#undef RD_BH
#undef VMW
#undef LGK
#undef BAR
#undef SBR

    // ---- epilogue: exchange b-acc via LDS, fuse bilinear coefficients ----
    __syncthreads();
    if (wr == 1) {
        #pragma unroll
        for (int i = 0; i < 8; ++i) {
            #pragma unroll
            for (int j = 0; j < 4; ++j) {
                const int off = ((((wc * 8 + i) * 4 + j) * 64) + lane) * 16;
                *(f32x4*)(smem + off) = acc[i][j];
            }
        }
    }
    __syncthreads();
    if (wr == 0) {
        const int hi = lane >> 4;
        #pragma unroll
        for (int i = 0; i < 8; ++i) {
            float4 cc[4];
            #pragma unroll
            for (int r = 0; r < 4; ++r) cc[r] = coef[m0 + i * 16 + hi * 4 + r];
            #pragma unroll
            for (int j = 0; j < 4; ++j) {
                const f32x4 bb = *(const f32x4*)(smem + ((((wc * 8 + i) * 4 + j) * 64) + lane) * 16);
                const int n = n0 + wc * 64 + j * 16 + fr;
                #pragma unroll
                for (int r = 0; r < 4; ++r) {
                    const int m = m0 + i * 16 + hi * 4 + r;
                    const float aa = acc[i][j][r];
                    out[(size_t)m * Nd + n] = cc[r].x + cc[r].y * aa + cc[r].z * bb[r]
                                            + cc[r].w * (aa * bb[r]);
                }
            }
        }
    }
}

// ---------------------------------------------------------------------------
extern "C" void kernel_launch(void* const* d_in, const int* in_sizes, int n_in,
                              void* d_out, int out_size, void* d_ws, size_t ws_size,
                              hipStream_t stream)
{
    const float* prev = (const float*)d_in[0];   // (prev_size, batch)
    const float* WA   = (const float*)d_in[1];   // (size, prev_size)
    const float* WB   = (const float*)d_in[2];   // (size, prev_size)
    const float* TW   = (const float*)d_in[3];   // (16, size)
    float* out = (float*)d_out;                  // (size, batch)

    const int size      = in_sizes[3] / 16;          // 1024
    const int prev_size = in_sizes[1] / size;        // 1024
    const int batch     = in_sizes[0] / prev_size;   // 16384

    char* ws = (char*)d_ws;
    __hip_bfloat16* prevT = (__hip_bfloat16*)ws;     // 32MB
    size_t off = (size_t)batch * prev_size * sizeof(__hip_bfloat16);
    __hip_bfloat16* pA = (__hip_bfloat16*)(ws + off);
    off += (size_t)size * prev_size * sizeof(__hip_bfloat16);
    __hip_bfloat16* pB = (__hip_bfloat16*)(ws + off);
    off += (size_t)size * prev_size * sizeof(__hip_bfloat16);
    float4* coef = (float4*)(ws + off);

    const int nprep = (batch / 64) * (prev_size / 64) + 2 * size + (size + 255) / 256;
    prep_fused<<<dim3(nprep), dim3(256), 0, stream>>>(
        prev, prevT, WA, WB, pA, pB, TW, coef);
    dual_gemm8<<<dim3(batch / 256, size / 128), dim3(512), 0, stream>>>(
        pA, pB, prevT, coef, out);
}